// Round 12
// baseline (599.589 us; speedup 1.0000x reference)
//
#include <hip/hip_runtime.h>

// Chamfer 2D exact NN, B=4, N=M=8192 — SINGLE-DISPATCH (R12).
// Out (flat f32): dist1[32768] | dist2[32768] | idx1[32768] | idx2[32768]
//
// One kernel, 1024 blocks x 256 threads, 5 phases split by DIY grid barriers
// (atomic counter + acquire spin; co-residency guaranteed: launch_bounds
// (256,6) + 11.3KB LDS => >=1536 blocks capacity > 1024 grid => no deadlock):
//   P1 histogram (16 sorts x 64 slices, global atomics)
//   P2 prefix-scan 16x1024 bins (blocks 0..15, validated shuffle scan)
//   P3 scatter to bpts (x-sorted) / ypts (y-sorted)   [global atomics]
//   P4 x-window scan, WIN=512, QPB=64 (R8-verbatim) -> global fail queue
//   P5 y-pass over queue, one wave/item, 4096 waves (R8-verbatim) + rare brute
// hist/cnt/barrier counters re-zeroed per replay by a captured hipMemsetAsync.
// Exactness (absmax=0, rounds 3-11): pair math __fmul_rn/__fadd_rn ==
// reference rounding; lex (d, orig_idx) == np.argmin first occurrence;
// bucket-edge certification conservative under RN monotonicity; single
// writer per output; results independent of nondeterministic scatter order.

#define NPTS 8192
#define NBUK 1024
#define XLO  (-6.0f)
#define XW   (0.01171875f)    // 12/1024 = 3*2^-8, exact; all edges exact floats
#define WIN  512
#define YWIN 512
#define QPB  64
#define UNI  (WIN + QPB)      // 576
#define NBLK 1024

__device__ __forceinline__ int bucket_of(float x) {
    int k = (int)floorf((x - XLO) * (1.0f / XW));
    k = k < 0 ? 0 : (k > NBUK - 1 ? NBUK - 1 : k);
    // enforce: k>0 -> x >= XLO+k*XW ; k<NBUK-1 -> x < XLO+(k+1)*XW
#pragma unroll
    for (int it = 0; it < 3; ++it) {
        if (k < NBUK - 1 && x >= XLO + (float)(k + 1) * XW) k++;
        else if (k > 0 && x < XLO + (float)k * XW) k--;
    }
    return k;
}

__device__ __forceinline__ void grid_bar(int* bar, int idx) {
    __threadfence();                 // all threads release prior writes
    __syncthreads();
    if (threadIdx.x == 0) {
        atomicAdd(&bar[idx], 1);
        while (__hip_atomic_load(&bar[idx], __ATOMIC_ACQUIRE,
                                 __HIP_MEMORY_SCOPE_AGENT) < NBLK) {}
    }
    __syncthreads();
}

__global__ __launch_bounds__(256, 6) void chamfer_coop(
    const float* __restrict__ in1, const float* __restrict__ in2,
    float4* __restrict__ bpts, float4* __restrict__ ypts,
    int* __restrict__ starts, int* __restrict__ cursors,
    int* __restrict__ hist, int* __restrict__ cnt,
    int* __restrict__ queue, int* __restrict__ bar,
    float* __restrict__ out)
{
    __shared__ float4 win[UNI];          // 9216 B
    __shared__ float pbd[4][QPB];
    __shared__ float pbz[4][QPB];
    __shared__ int wsum[4];

    const int bid = blockIdx.x;
    const int t   = threadIdx.x;

    // ---- P1: histogram. block -> (sort, slice); 128 points/block ----------
    const int sort  = bid >> 6;          // 0..15 ; mode = sort>>3, sb = sort&7
    const int slice = bid & 63;
    const int smode = sort >> 3;
    const int ssb   = sort & 7;
    float2 myxy = make_float2(0.f, 0.f);
    int myk = -1;
    if (t < 128) {
        const float2* __restrict__ src = (const float2*)(
            ((ssb >= 4) ? in2 : in1) + (size_t)(ssb & 3) * NPTS * 2);
        myxy = src[(slice << 7) + t];
        myk  = bucket_of(smode ? myxy.y : myxy.x);
        atomicAdd(&hist[(sort << 10) + myk], 1);
    }
    grid_bar(bar, 0);

    // ---- P2: exclusive scan of each sort's 1024 bins (blocks 0..15) -------
    if (bid < 16) {
        const int base = bid << 10;
        const int i0 = t << 2;
        const int h0 = hist[base + i0],     h1 = hist[base + i0 + 1];
        const int h2 = hist[base + i0 + 2], h3 = hist[base + i0 + 3];
        const int s1 = h0 + h1, s2 = s1 + h2, s3 = s2 + h3;
        int inc = s3;
        const int lane = t & 63, w = t >> 6;
#pragma unroll
        for (int d = 1; d < 64; d <<= 1) {
            const int o = __shfl_up(inc, d, 64);
            if (lane >= d) inc += o;
        }
        if (lane == 63) wsum[w] = inc;
        __syncthreads();
        int excl = inc - s3;                 // exclusive within wave
#pragma unroll
        for (int k = 0; k < 3; ++k) if (k < w) excl += wsum[k];
        starts[bid * 1025 + i0]     = excl;      cursors[base + i0]     = excl;
        starts[bid * 1025 + i0 + 1] = excl + h0; cursors[base + i0 + 1] = excl + h0;
        starts[bid * 1025 + i0 + 2] = excl + s1; cursors[base + i0 + 2] = excl + s1;
        starts[bid * 1025 + i0 + 3] = excl + s2; cursors[base + i0 + 3] = excl + s2;
        if (t == 0) starts[bid * 1025 + NBUK] = NPTS;
    }
    grid_bar(bar, 1);

    // ---- P3: scatter (bucket-internal order nondeterministic; outputs
    // stay exact via explicit lex (d, idx) tie-break at query time) ---------
    if (myk >= 0) {
        const int pos = atomicAdd(&cursors[(sort << 10) + myk], 1);
        float4* __restrict__ dst = (smode ? ypts : bpts) + (size_t)ssb * NPTS;
        dst[pos] = make_float4(myxy.x, myxy.y, (float)((slice << 7) + t), 0.0f);
    }
    grid_bar(bar, 2);

    // ---- P4: x-window scan (R8-verbatim; WIN=512, QPB=64) -----------------
    {
        const int q0slot = bid * QPB;
        const int db  = q0slot >> 13;        // dir*4 + b
        const int dir = db >> 2;
        const int b   = db & 3;
        const int q0  = q0slot & 8191;
        const int qsb = (dir ? 4 : 0) + b;
        const int rsb = (dir ? 0 : 4) + b;

        const float4* __restrict__ Q  = bpts + (size_t)qsb * NPTS;
        const float4* __restrict__ Rf = bpts + (size_t)rsb * NPTS;

        int u0 = q0 - WIN / 2;
        u0 = u0 < 0 ? 0 : (u0 > NPTS - UNI ? NPTS - UNI : u0);

        win[t]       = Rf[u0 + t];
        win[t + 256] = Rf[u0 + 256 + t];
        if (t < UNI - 512) win[t + 512] = Rf[u0 + 512 + t];
        __syncthreads();

        const int s = t >> 6;                // wave id = candidate chunk
        const int L = t & 63;                // lane (wave0: query-in-block)
        const int qpos = q0 + L;
        const float4 q = Q[qpos];
        const float qx = q.x, qy = q.y;

        int wl = qpos - WIN / 2;
        wl = wl < 0 ? 0 : (wl > NPTS - WIN ? NPTS - WIN : wl);
        const int base = (wl - u0) + (s << 7);

        float bd0 = 1e30f, bd1 = 1e30f, bz0 = 0.0f, bz1 = 0.0f;
        for (int i = 0; i < 128; i += 8) {
#pragma unroll
            for (int u = 0; u < 8; ++u) {
                const float4 r = win[base + i + u];
                const float dx = qx - r.x;
                const float dy = qy - r.y;
                // identical rounding to reference: (dx*dx)+(dy*dy), no FMA
                const float d = __fadd_rn(__fmul_rn(dx, dx), __fmul_rn(dy, dy));
                if (u & 1) {
                    const bool c = (d < bd1) || (d == bd1 && r.z < bz1);
                    bd1 = c ? d : bd1; bz1 = c ? r.z : bz1;
                } else {
                    const bool c = (d < bd0) || (d == bd0 && r.z < bz0);
                    bd0 = c ? d : bd0; bz0 = c ? r.z : bz0;
                }
            }
        }
        const bool cm = (bd1 < bd0) || (bd1 == bd0 && bz1 < bz0);
        pbd[s][L] = cm ? bd1 : bd0;
        pbz[s][L] = cm ? bz1 : bz0;
        __syncthreads();

        if (t < QPB) {                       // wave 0: combine, certify
            float best = pbd[0][L];
            float bif  = pbz[0][L];
#pragma unroll
            for (int k = 1; k < 4; ++k) {
                const float dv = pbd[k][L];
                const float zv = pbz[k][L];
                const bool c = (dv < best) || (dv == best && zv < bif);
                best = c ? dv : best;
                bif  = c ? zv : bif;
            }

            const int wr = wl + WIN;
            bool okL = (wl == 0), okR = (wr >= NPTS);
            if (!okL) {
                const int kl = bucket_of(Rf[wl - 1].x);
                if (kl < NBUK - 1) {
                    const float dxe = qx - (XLO + (float)(kl + 1) * XW);
                    okL = (dxe > 0.0f) && (__fmul_rn(dxe, dxe) > best);
                }
            }
            if (!okR) {
                const int kr = bucket_of(Rf[wr].x);
                if (kr > 0) {
                    const float dxe = (XLO + (float)kr * XW) - qx;
                    okR = (dxe > 0.0f) && (__fmul_rn(dxe, dxe) > best);
                }
            }

            if (okL && okR) {                // certified: sole writer here
                const int qid = (int)q.z;
                const int od  = b * 8192 + qid;
                if (dir == 0) { out[od]         = best; out[65536 + od] = bif; }
                else          { out[32768 + od] = best; out[98304 + od] = bif; }
            } else {
                const int pos = atomicAdd(cnt, 1);
                queue[pos] = q0slot + L;
                // carried best re-read by P5 from out: stash it there too
                const int qid = (int)q.z;
                const int od  = b * 8192 + qid;
                if (dir == 0) { out[od]         = best; out[65536 + od] = bif; }
                else          { out[32768 + od] = best; out[98304 + od] = bif; }
            }
        }
    }
    grid_bar(bar, 3);

    // ---- P5: y-pass over fail queue, one wave per item (R8-verbatim) ------
    {
        const int n    = *cnt;
        const int gw   = (bid << 2) + (t >> 6);
        const int lane = t & 63;

        for (int item = gw; item < n; item += NBLK * 4) {
            const int qslot = queue[item];
            const int qpos  = qslot & 8191;
            const int db    = qslot >> 13;
            const int dir   = db >> 2;
            const int b     = db & 3;
            const int qsb   = (dir ? 4 : 0) + b;
            const int rsb   = (dir ? 0 : 4) + b;

            const float4 q = bpts[(size_t)qsb * NPTS + qpos];
            const float qx = q.x, qy = q.y;
            const int qid  = (int)q.z;
            const int od   = b * 8192 + qid;

            float best = (dir == 0) ? out[od]         : out[32768 + od];
            float bif  = (dir == 0) ? out[65536 + od] : out[98304 + od];

            const float4* __restrict__ Y = ypts + (size_t)rsb * NPTS;
            const int* __restrict__ ys   = starts + (8 + rsb) * 1025;
            const int kq = bucket_of(qy);
            int wl = ((ys[kq] + ys[kq + 1]) >> 1) - YWIN / 2;
            wl = wl < 0 ? 0 : (wl > NPTS - YWIN ? NPTS - YWIN : wl);

            float bd = 1e30f, bz = 0.0f;
#pragma unroll
            for (int i = 0; i < 8; ++i) {
                const float4 r = Y[wl + lane + (i << 6)];
                const float dx = qx - r.x;
                const float dy = qy - r.y;
                const float d = __fadd_rn(__fmul_rn(dx, dx), __fmul_rn(dy, dy));
                const bool c = (d < bd) || (d == bd && r.z < bz);
                bd = c ? d : bd;
                bz = c ? r.z : bz;
            }
#pragma unroll
            for (int m = 1; m < 64; m <<= 1) {
                const float od_ = __shfl_xor(bd, m, 64);
                const float oz_ = __shfl_xor(bz, m, 64);
                const bool c = (od_ < bd) || (od_ == bd && oz_ < bz);
                bd = c ? od_ : bd;
                bz = c ? oz_ : bz;
            }
            {
                const bool c = (bd < best) || (bd == best && bz < bif);
                best = c ? bd : best;
                bif  = c ? bz : bif;
            }

            // y-edge certification (unscanned => y-gap >= dye => d >= fl(dye^2))
            const int wr = wl + YWIN;
            bool okL = (wl == 0), okR = (wr >= NPTS);
            if (!okL) {
                const int kl = bucket_of(Y[wl - 1].y);
                if (kl < NBUK - 1) {
                    const float dye = qy - (XLO + (float)(kl + 1) * XW);
                    okL = (dye > 0.0f) && (__fmul_rn(dye, dye) > best);
                }
            }
            if (!okR) {
                const int kr = bucket_of(Y[wr].y);
                if (kr > 0) {
                    const float dye = (XLO + (float)kr * XW) - qy;
                    okR = (dye > 0.0f) && (__fmul_rn(dye, dye) > best);
                }
            }

            if (!(okL && okR)) {
                // double-fail: exact brute force over idx-ordered array
                const float2* __restrict__ P =
                    (const float2*)((dir ? in1 : in2) + (size_t)b * NPTS * 2);
                float fbd = 1e30f, fbz = 0.0f;
#pragma unroll 4
                for (int j = lane; j < NPTS; j += 64) {
                    const float2 rp = P[j];
                    const float dx = qx - rp.x;
                    const float dy = qy - rp.y;
                    const float d = __fadd_rn(__fmul_rn(dx, dx), __fmul_rn(dy, dy));
                    const bool c = d < fbd;
                    fbd = c ? d : fbd;
                    fbz = c ? (float)j : fbz;
                }
#pragma unroll
                for (int m = 1; m < 64; m <<= 1) {
                    const float od_ = __shfl_xor(fbd, m, 64);
                    const float oz_ = __shfl_xor(fbz, m, 64);
                    const bool c = (od_ < fbd) || (od_ == fbd && oz_ < fbz);
                    fbd = c ? od_ : fbd;
                    fbz = c ? oz_ : fbz;
                }
                best = fbd;
                bif  = fbz;
            }

            if (lane == 0) {                 // handling wave is sole writer now
                if (dir == 0) { out[od]         = best; out[65536 + od] = bif; }
                else          { out[32768 + od] = best; out[98304 + od] = bif; }
            }
        }
    }
}

extern "C" void kernel_launch(void* const* d_in, const int* in_sizes, int n_in,
                              void* d_out, int out_size, void* d_ws, size_t ws_size,
                              hipStream_t stream) {
    const float* in1 = (const float*)d_in[0];
    const float* in2 = (const float*)d_in[1];
    float* out = (float*)d_out;
    (void)in_sizes; (void)n_in; (void)out_size; (void)ws_size;

    // ws layout (bytes):
    //   bpts    @ 0          1 MiB
    //   ypts    @ 1 MiB      1 MiB
    //   starts  @ 2097152    16*1025*4 = 65600
    //   cursors @ 2162752    16*1024*4 = 65536
    //   hist    @ 2228288    65536   <-- memset 0 (with cnt+bar, one call)
    //   cnt     @ 2293824    4
    //   bar     @ 2293828    16
    //   queue   @ 2293844    65536*4
    char* w = (char*)d_ws;
    float4* bpts   = (float4*)(w);
    float4* ypts   = (float4*)(w + 1048576);
    int*    starts = (int*)(w + 2097152);
    int*    cursors= (int*)(w + 2162752);
    int*    hist   = (int*)(w + 2228288);
    int*    cnt    = (int*)(w + 2293824);
    int*    bar    = (int*)(w + 2293828);
    int*    queue  = (int*)(w + 2293844);

    // re-zero hist + cnt + bar each call (captured into the graph)
    hipMemsetAsync(hist, 0, 65536 + 4 + 16, stream);

    chamfer_coop<<<NBLK, 256, 0, stream>>>(in1, in2, bpts, ypts, starts,
                                           cursors, hist, cnt, queue, bar, out);
}

// Round 13
// 44.385 us; speedup vs baseline: 13.5088x; 13.5088x over previous
//
#include <hip/hip_runtime.h>

// Chamfer 2D exact NN, B=4, N=M=8192.
// Out (flat f32): dist1[32768] | dist2[32768] | idx1[32768] | idx2[32768]
//
// R13 = R8 (best: 46.9us) with ONE change: the x-window scan inner loop is
// explicitly software-pipelined — 8 named float4 ds_reads issued before any
// compute (R8/R10 compiled to VGPR=20 => compiler re-rolled the unroll-8 into
// serial ds_read->wait->compute, ~1 outstanding LDS read/wave; window_scan
// sat at ~30us vs its ~10us DS-throughput floor). Everything else verbatim:
//  1) bucketize (16 blocks): 8 x-sorts -> bpts, 8 y-sorts -> ypts + ystarts.
//  2) x-window scan: WIN=512, QPB=64, x-edge certification; fails -> queue.
//  3) y-pass: one wave per queued query (2048 waves), 512-rank y-window +
//     y-cert + rare brute force.
// Exactness (absmax=0, rounds 3-12): pair math __fmul_rn/__fadd_rn ==
// reference rounding; lex (d, orig_idx) == np.argmin first occurrence;
// bucket-edge certification conservative under RN monotonicity; single
// writer per output; deterministic despite nondeterministic bucket order.

#define NPTS 8192
#define NBUK 1024
#define XLO  (-6.0f)
#define XW   (0.01171875f)    // 12/1024 = 3*2^-8, exact; all edges exact floats
#define WIN  512
#define YWIN 512
#define QPB  64
#define UNI  (WIN + QPB)      // 576

__device__ __forceinline__ int bucket_of(float x) {
    int k = (int)floorf((x - XLO) * (1.0f / XW));
    k = k < 0 ? 0 : (k > NBUK - 1 ? NBUK - 1 : k);
    // enforce: k>0 -> x >= XLO+k*XW ; k<NBUK-1 -> x < XLO+(k+1)*XW
#pragma unroll
    for (int it = 0; it < 3; ++it) {
        if (k < NBUK - 1 && x >= XLO + (float)(k + 1) * XW) k++;
        else if (k > 0 && x < XLO + (float)k * XW) k--;
    }
    return k;
}

// ---- 1) bucketize: 16 blocks (mode = bid>>3: 0 x-sort, 1 y-sort) ----------
__global__ __launch_bounds__(1024) void bucketize_kernel(
    const float* __restrict__ in1, const float* __restrict__ in2,
    float4* __restrict__ bpts, float4* __restrict__ ypts,
    int* __restrict__ ystarts, int* __restrict__ cnt)
{
    __shared__ float4 spts[NPTS];   // 128 KB sorted staging
    __shared__ int h[NBUK];         // counts -> exclusive starts -> cursors
    __shared__ int wsum[16];        // per-wave scan partials

    const int mode = blockIdx.x >> 3;          // 0: x-key, 1: y-key
    const int sb   = blockIdx.x & 7;           // set*4 + b
    const float2* __restrict__ src =
        (const float2*)(((sb >= 4) ? in2 : in1) + (size_t)(sb & 3) * NPTS * 2);
    const int t    = threadIdx.x;
    const int lane = t & 63;
    const int w    = t >> 6;

    h[t] = 0;
    if (blockIdx.x == 0 && t == 0) *cnt = 0;
    __syncthreads();

    // pass 1: load 8 points/thread into registers, count buckets
    float px[8], py[8];
    int   pk[8];
#pragma unroll
    for (int i = 0; i < 8; ++i) {
        const float2 xy = src[t + (i << 10)];
        px[i] = xy.x; py[i] = xy.y;
        pk[i] = bucket_of(mode ? xy.y : xy.x);
        atomicAdd(&h[pk[i]], 1);
    }
    __syncthreads();

    // exclusive prefix scan of h[1024]: wave shuffle scan + 16 partials
    const int v = h[t];
    int inc = v;
#pragma unroll
    for (int d = 1; d < 64; d <<= 1) {
        const int o = __shfl_up(inc, d, 64);
        if (lane >= d) inc += o;
    }
    if (lane == 63) wsum[w] = inc;
    __syncthreads();
    if (t < 16) {                    // wave 0 scans the 16 wave totals
        int pv = wsum[t];
        int pinc = pv;
#pragma unroll
        for (int d = 1; d < 16; d <<= 1) {
            const int o = __shfl_up(pinc, d, 64);
            if (lane >= d) pinc += o;
        }
        wsum[t] = pinc - pv;         // exclusive wave offset
    }
    __syncthreads();
    const int excl = (inc - v) + wsum[w];   // exclusive start
    h[t] = excl;
    if (mode) {
        ystarts[sb * (NBUK + 1) + t] = excl;
        if (t == 0) ystarts[sb * (NBUK + 1) + NBUK] = NPTS;
    }
    __syncthreads();

    // pass 2: place into LDS at sorted positions (cheap LDS scatter)
#pragma unroll
    for (int i = 0; i < 8; ++i) {
        const int pos = atomicAdd(&h[pk[i]], 1);
        spts[pos] = make_float4(px[i], py[i], (float)(t + (i << 10)), 0.0f);
    }
    __syncthreads();

    // linear coalesced writeback
    float4* __restrict__ dst = (mode ? ypts : bpts) + (size_t)sb * NPTS;
#pragma unroll
    for (int i = 0; i < 8; ++i)
        dst[t + (i << 10)] = spts[t + (i << 10)];
}

// ---- 2) x-window scan: 1024 blocks, 64 queries/block, pipelined loads -----
__global__ __launch_bounds__(256) void window_scan_kernel(
    const float4* __restrict__ bpts, float* __restrict__ out,
    int* __restrict__ cnt, int* __restrict__ queue)
{
    __shared__ float4 win[UNI];          // 9216 B
    __shared__ float pbd[4][QPB];
    __shared__ float pbz[4][QPB];

    const int bid = blockIdx.x;
    const int t   = threadIdx.x;
    const int q0slot = bid * QPB;        // first qslot of block
    const int db  = q0slot >> 13;        // dir*4 + b  (64 | 8192: no straddle)
    const int dir = db >> 2;
    const int b   = db & 3;
    const int q0  = q0slot & 8191;
    const int qsb = (dir ? 4 : 0) + b;
    const int rsb = (dir ? 0 : 4) + b;

    const float4* __restrict__ Q  = bpts + (size_t)qsb * NPTS;
    const float4* __restrict__ Rf = bpts + (size_t)rsb * NPTS;

    int u0 = q0 - WIN / 2;
    u0 = u0 < 0 ? 0 : (u0 > NPTS - UNI ? NPTS - UNI : u0);

    // stage union [u0, u0+576): coalesced float4 loads
    win[t]       = Rf[u0 + t];
    win[t + 256] = Rf[u0 + 256 + t];
    if (t < UNI - 512) win[t + 512] = Rf[u0 + 512 + t];
    __syncthreads();

    const int s = t >> 6;                // wave id = candidate chunk
    const int L = t & 63;                // lane = query-in-block
    const int qpos = q0 + L;
    const float4 q = Q[qpos];
    const float qx = q.x, qy = q.y;

    int wl = qpos - WIN / 2;
    wl = wl < 0 ? 0 : (wl > NPTS - WIN ? NPTS - WIN : wl);
    const int base = (wl - u0) + (s << 7);   // lane-contiguous -> conflict-free

    // two independent lex-min chains; 8 named ds_reads issued per group so
    // 8 LDS reads stay in flight per wave (defeats compiler re-rolling).
    float bd0 = 1e30f, bd1 = 1e30f, bz0 = 0.0f, bz1 = 0.0f;
    for (int i = 0; i < 128; i += 8) {
        const float4 r0 = win[base + i + 0];
        const float4 r1 = win[base + i + 1];
        const float4 r2 = win[base + i + 2];
        const float4 r3 = win[base + i + 3];
        const float4 r4 = win[base + i + 4];
        const float4 r5 = win[base + i + 5];
        const float4 r6 = win[base + i + 6];
        const float4 r7 = win[base + i + 7];

#define STEP0(r) { const float dx = qx - (r).x, dy = qy - (r).y;              \
        const float d = __fadd_rn(__fmul_rn(dx, dx), __fmul_rn(dy, dy));      \
        const bool c = (d < bd0) || (d == bd0 && (r).z < bz0);                \
        bd0 = c ? d : bd0; bz0 = c ? (r).z : bz0; }
#define STEP1(r) { const float dx = qx - (r).x, dy = qy - (r).y;              \
        const float d = __fadd_rn(__fmul_rn(dx, dx), __fmul_rn(dy, dy));      \
        const bool c = (d < bd1) || (d == bd1 && (r).z < bz1);                \
        bd1 = c ? d : bd1; bz1 = c ? (r).z : bz1; }
        STEP0(r0) STEP1(r1) STEP0(r2) STEP1(r3)
        STEP0(r4) STEP1(r5) STEP0(r6) STEP1(r7)
#undef STEP0
#undef STEP1
    }
    const bool cm = (bd1 < bd0) || (bd1 == bd0 && bz1 < bz0);
    pbd[s][L] = cm ? bd1 : bd0;
    pbz[s][L] = cm ? bz1 : bz0;
    __syncthreads();

    if (t < QPB) {                       // wave 0: combine, certify, write
        float best = pbd[0][L];
        float bif  = pbz[0][L];
#pragma unroll
        for (int k = 1; k < 4; ++k) {
            const float dv = pbd[k][L];
            const float zv = pbz[k][L];
            const bool c = (dv < best) || (dv == best && zv < bif);
            best = c ? dv : best;
            bif  = c ? zv : bif;
        }

        // exact-conservative certification (x):
        //  all p<wl have x <= right_edge(bucket(x[wl-1])) and
        //  d >= fl(dx^2) >= fl(dxe^2) > best => can't beat or tie
        const int wr = wl + WIN;
        bool okL = (wl == 0), okR = (wr >= NPTS);
        if (!okL) {
            const int kl = bucket_of(Rf[wl - 1].x);
            if (kl < NBUK - 1) {
                const float dxe = qx - (XLO + (float)(kl + 1) * XW);
                okL = (dxe > 0.0f) && (__fmul_rn(dxe, dxe) > best);
            }
        }
        if (!okR) {
            const int kr = bucket_of(Rf[wr].x);
            if (kr > 0) {
                const float dxe = (XLO + (float)kr * XW) - qx;
                okR = (dxe > 0.0f) && (__fmul_rn(dxe, dxe) > best);
            }
        }

        const int qid = (int)q.z;
        const int od  = b * 8192 + qid;
        if (dir == 0) { out[od]         = best; out[65536 + od] = bif; }
        else          { out[32768 + od] = best; out[98304 + od] = bif; }

        if (!(okL && okR)) {
            const int pos = atomicAdd(cnt, 1);
            queue[pos] = q0slot + L;     // db*8192 + qpos
        }
    }
}

// ---- 3) y-pass: one wave per queued query (2048 waves) --------------------
__global__ __launch_bounds__(256) void ypass_kernel(
    const float4* __restrict__ bpts, const float4* __restrict__ ypts,
    const int* __restrict__ ystarts, const float* __restrict__ in1,
    const float* __restrict__ in2, const int* __restrict__ cnt,
    const int* __restrict__ queue, float* __restrict__ out)
{
    const int n    = *cnt;
    const int gw   = (blockIdx.x << 2) + (threadIdx.x >> 6);
    const int lane = threadIdx.x & 63;

    for (int item = gw; item < n; item += 2048) {
        const int qslot = queue[item];
        const int qpos  = qslot & 8191;
        const int db    = qslot >> 13;
        const int dir   = db >> 2;
        const int b     = db & 3;
        const int qsb   = (dir ? 4 : 0) + b;
        const int rsb   = (dir ? 0 : 4) + b;

        const float4 q = bpts[(size_t)qsb * NPTS + qpos];
        const float qx = q.x, qy = q.y;
        const int qid  = (int)q.z;
        const int od   = b * 8192 + qid;

        // carried pass-1 lex-min (over the x-window)
        float best = (dir == 0) ? out[od]         : out[32768 + od];
        float bif  = (dir == 0) ? out[65536 + od] : out[98304 + od];

        // y-rank window centered via ystarts
        const float4* __restrict__ Y  = ypts + (size_t)rsb * NPTS;
        const int* __restrict__ ys    = ystarts + rsb * (NBUK + 1);
        const int kq = bucket_of(qy);
        int wl = ((ys[kq] + ys[kq + 1]) >> 1) - YWIN / 2;
        wl = wl < 0 ? 0 : (wl > NPTS - YWIN ? NPTS - YWIN : wl);

        // scan 512 y-ranked candidates: lane + 64*i, coalesced
        float bd = 1e30f, bz = 0.0f;
#pragma unroll
        for (int i = 0; i < 8; ++i) {
            const float4 r = Y[wl + lane + (i << 6)];
            const float dx = qx - r.x;
            const float dy = qy - r.y;
            const float d = __fadd_rn(__fmul_rn(dx, dx), __fmul_rn(dy, dy));
            const bool c = (d < bd) || (d == bd && r.z < bz);
            bd = c ? d : bd;
            bz = c ? r.z : bz;
        }
        // butterfly lex reduce -> all lanes hold the window min
#pragma unroll
        for (int m = 1; m < 64; m <<= 1) {
            const float od_ = __shfl_xor(bd, m, 64);
            const float oz_ = __shfl_xor(bz, m, 64);
            const bool c = (od_ < bd) || (od_ == bd && oz_ < bz);
            bd = c ? od_ : bd;
            bz = c ? oz_ : bz;
        }
        // combine with carried best
        {
            const bool c = (bd < best) || (bd == best && bz < bif);
            best = c ? bd : best;
            bif  = c ? bz : bif;
        }

        // y-edge certification (sufficient alone: any unscanned point p has
        // y-gap >= dye => d >= fl(dy^2) >= fl(dye^2) > best)
        const int wr = wl + YWIN;
        bool okL = (wl == 0), okR = (wr >= NPTS);
        if (!okL) {
            const int kl = bucket_of(Y[wl - 1].y);
            if (kl < NBUK - 1) {
                const float dye = qy - (XLO + (float)(kl + 1) * XW);
                okL = (dye > 0.0f) && (__fmul_rn(dye, dye) > best);
            }
        }
        if (!okR) {
            const int kr = bucket_of(Y[wr].y);
            if (kr > 0) {
                const float dye = (XLO + (float)kr * XW) - qy;
                okR = (dye > 0.0f) && (__fmul_rn(dye, dye) > best);
            }
        }

        if (!(okL && okR)) {
            // double-fail: exact brute force over idx-ordered original array.
            // per-lane j ascends -> strict < keeps first occurrence in-lane.
            const float2* __restrict__ P =
                (const float2*)((dir ? in1 : in2) + (size_t)b * NPTS * 2);
            float fbd = 1e30f, fbz = 0.0f;
#pragma unroll 4
            for (int j = lane; j < NPTS; j += 64) {
                const float2 rp = P[j];
                const float dx = qx - rp.x;
                const float dy = qy - rp.y;
                const float d = __fadd_rn(__fmul_rn(dx, dx), __fmul_rn(dy, dy));
                const bool c = d < fbd;
                fbd = c ? d : fbd;
                fbz = c ? (float)j : fbz;
            }
#pragma unroll
            for (int m = 1; m < 64; m <<= 1) {
                const float od_ = __shfl_xor(fbd, m, 64);
                const float oz_ = __shfl_xor(fbz, m, 64);
                const bool c = (od_ < fbd) || (od_ == fbd && oz_ < fbz);
                fbd = c ? od_ : fbd;
                fbz = c ? oz_ : fbz;
            }
            best = fbd;
            bif  = fbz;
        }

        if (lane == 0) {
            if (dir == 0) { out[od]         = best; out[65536 + od] = bif; }
            else          { out[32768 + od] = best; out[98304 + od] = bif; }
        }
    }
}

extern "C" void kernel_launch(void* const* d_in, const int* in_sizes, int n_in,
                              void* d_out, int out_size, void* d_ws, size_t ws_size,
                              hipStream_t stream) {
    const float* in1 = (const float*)d_in[0];
    const float* in2 = (const float*)d_in[1];
    float* out = (float*)d_out;
    (void)in_sizes; (void)n_in; (void)out_size; (void)ws_size;

    // ws: bpts 1MiB | ypts 1MiB | ystarts 8*1025*4 | cnt 4 | queue 65536*4
    char* w = (char*)d_ws;
    float4* bpts = (float4*)w;
    float4* ypts = (float4*)(w + (size_t)8 * NPTS * sizeof(float4));
    int* ystarts = (int*)(w + (size_t)16 * NPTS * sizeof(float4));
    int* cnt     = ystarts + 8 * (NBUK + 1);
    int* queue   = cnt + 1;

    bucketize_kernel<<<16, 1024, 0, stream>>>(in1, in2, bpts, ypts, ystarts, cnt);
    window_scan_kernel<<<(2 * 4 * NPTS) / QPB, 256, 0, stream>>>(bpts, out, cnt, queue);
    ypass_kernel<<<512, 256, 0, stream>>>(bpts, ypts, ystarts, in1, in2,
                                          cnt, queue, out);
}

// Round 14
// 39.599 us; speedup vs baseline: 15.1415x; 1.1209x over previous
//
#include <hip/hip_runtime.h>

// Chamfer 2D exact NN, B=4, N=M=8192.
// Out (flat f32): dist1[32768] | dist2[32768] | idx1[32768] | idx2[32768]
//
// R14 = R13 with ONE change: the x-window scan uses BROADCAST candidate
// reads. Old: lane=query-chunk pairing, per-lane ds_read_b128 addresses ->
// 512KB LDS traffic per block (the ~27us cost). New: every wave holds all 64
// queries (lane = query); candidates are read one at a time at a wave-UNIFORM
// address (hardware broadcast, 16B/instr); wave s scans union quarter
// [s*144, s*144+144). LDS traffic drops 50x; kernel becomes VALU-bound.
// Every query scans the full 576-union (superset of its 512-window) and
// certifies at the union edges u0-1 / u0+UNI — same conservative proof.
//  1) bucketize (16 blocks): 8 x-sorts -> bpts, 8 y-sorts -> ypts + ystarts.
//  2) x-union scan (this kernel): QPB=64, fails -> queue.
//  3) y-pass: one wave per queued query, 512-rank y-window + y-cert + brute.
// Exactness (absmax=0, rounds 3-13): pair math __fmul_rn/__fadd_rn ==
// reference rounding; lex (d, orig_idx) == np.argmin first occurrence;
// bucket-edge certification conservative under RN monotonicity; single
// writer per output; deterministic despite nondeterministic bucket order.

#define NPTS 8192
#define NBUK 1024
#define XLO  (-6.0f)
#define XW   (0.01171875f)    // 12/1024 = 3*2^-8, exact; all edges exact floats
#define WIN  512
#define YWIN 512
#define QPB  64
#define UNI  (WIN + QPB)      // 576 staged candidates; 144 per wave
#define CPW  (UNI / 4)        // candidates per wave

__device__ __forceinline__ int bucket_of(float x) {
    int k = (int)floorf((x - XLO) * (1.0f / XW));
    k = k < 0 ? 0 : (k > NBUK - 1 ? NBUK - 1 : k);
    // enforce: k>0 -> x >= XLO+k*XW ; k<NBUK-1 -> x < XLO+(k+1)*XW
#pragma unroll
    for (int it = 0; it < 3; ++it) {
        if (k < NBUK - 1 && x >= XLO + (float)(k + 1) * XW) k++;
        else if (k > 0 && x < XLO + (float)k * XW) k--;
    }
    return k;
}

// ---- 1) bucketize: 16 blocks (mode = bid>>3: 0 x-sort, 1 y-sort) ----------
__global__ __launch_bounds__(1024) void bucketize_kernel(
    const float* __restrict__ in1, const float* __restrict__ in2,
    float4* __restrict__ bpts, float4* __restrict__ ypts,
    int* __restrict__ ystarts, int* __restrict__ cnt)
{
    __shared__ float4 spts[NPTS];   // 128 KB sorted staging
    __shared__ int h[NBUK];         // counts -> exclusive starts -> cursors
    __shared__ int wsum[16];        // per-wave scan partials

    const int mode = blockIdx.x >> 3;          // 0: x-key, 1: y-key
    const int sb   = blockIdx.x & 7;           // set*4 + b
    const float2* __restrict__ src =
        (const float2*)(((sb >= 4) ? in2 : in1) + (size_t)(sb & 3) * NPTS * 2);
    const int t    = threadIdx.x;
    const int lane = t & 63;
    const int w    = t >> 6;

    h[t] = 0;
    if (blockIdx.x == 0 && t == 0) *cnt = 0;
    __syncthreads();

    // pass 1: load 8 points/thread into registers, count buckets
    float px[8], py[8];
    int   pk[8];
#pragma unroll
    for (int i = 0; i < 8; ++i) {
        const float2 xy = src[t + (i << 10)];
        px[i] = xy.x; py[i] = xy.y;
        pk[i] = bucket_of(mode ? xy.y : xy.x);
        atomicAdd(&h[pk[i]], 1);
    }
    __syncthreads();

    // exclusive prefix scan of h[1024]: wave shuffle scan + 16 partials
    const int v = h[t];
    int inc = v;
#pragma unroll
    for (int d = 1; d < 64; d <<= 1) {
        const int o = __shfl_up(inc, d, 64);
        if (lane >= d) inc += o;
    }
    if (lane == 63) wsum[w] = inc;
    __syncthreads();
    if (t < 16) {                    // wave 0 scans the 16 wave totals
        int pv = wsum[t];
        int pinc = pv;
#pragma unroll
        for (int d = 1; d < 16; d <<= 1) {
            const int o = __shfl_up(pinc, d, 64);
            if (lane >= d) pinc += o;
        }
        wsum[t] = pinc - pv;         // exclusive wave offset
    }
    __syncthreads();
    const int excl = (inc - v) + wsum[w];   // exclusive start
    h[t] = excl;
    if (mode) {
        ystarts[sb * (NBUK + 1) + t] = excl;
        if (t == 0) ystarts[sb * (NBUK + 1) + NBUK] = NPTS;
    }
    __syncthreads();

    // pass 2: place into LDS at sorted positions (cheap LDS scatter)
#pragma unroll
    for (int i = 0; i < 8; ++i) {
        const int pos = atomicAdd(&h[pk[i]], 1);
        spts[pos] = make_float4(px[i], py[i], (float)(t + (i << 10)), 0.0f);
    }
    __syncthreads();

    // linear coalesced writeback
    float4* __restrict__ dst = (mode ? ypts : bpts) + (size_t)sb * NPTS;
#pragma unroll
    for (int i = 0; i < 8; ++i)
        dst[t + (i << 10)] = spts[t + (i << 10)];
}

// ---- 2) x-union scan: 1024 blocks, 64 queries/block, broadcast cands ------
__global__ __launch_bounds__(256) void window_scan_kernel(
    const float4* __restrict__ bpts, float* __restrict__ out,
    int* __restrict__ cnt, int* __restrict__ queue)
{
    __shared__ float4 win[UNI];          // 9216 B
    __shared__ float pbd[4][QPB];
    __shared__ float pbz[4][QPB];

    const int bid = blockIdx.x;
    const int t   = threadIdx.x;
    const int q0slot = bid * QPB;        // first qslot of block
    const int db  = q0slot >> 13;        // dir*4 + b  (64 | 8192: no straddle)
    const int dir = db >> 2;
    const int b   = db & 3;
    const int q0  = q0slot & 8191;
    const int qsb = (dir ? 4 : 0) + b;
    const int rsb = (dir ? 0 : 4) + b;

    const float4* __restrict__ Q  = bpts + (size_t)qsb * NPTS;
    const float4* __restrict__ Rf = bpts + (size_t)rsb * NPTS;

    int u0 = q0 + QPB / 2 - UNI / 2;     // center union on block's query span
    u0 = u0 < 0 ? 0 : (u0 > NPTS - UNI ? NPTS - UNI : u0);

    // stage union [u0, u0+576): coalesced float4 loads
    win[t]       = Rf[u0 + t];
    win[t + 256] = Rf[u0 + 256 + t];
    if (t < UNI - 512) win[t + 512] = Rf[u0 + 512 + t];
    __syncthreads();

    const int s = t >> 6;                // wave id -> union quarter
    const int L = t & 63;                // lane = query-in-block
    const float4 q = Q[q0 + L];
    const float qx = q.x, qy = q.y;

    // every wave holds all 64 queries; candidates broadcast (uniform addr).
    // two independent lex-min chains; 8 named reads in flight per group.
    float bd0 = 1e30f, bd1 = 1e30f, bz0 = 0.0f, bz1 = 0.0f;
    const int c0 = s * CPW;              // 144 candidates per wave
    for (int i = 0; i < CPW; i += 8) {
        const float4 r0 = win[c0 + i + 0];
        const float4 r1 = win[c0 + i + 1];
        const float4 r2 = win[c0 + i + 2];
        const float4 r3 = win[c0 + i + 3];
        const float4 r4 = win[c0 + i + 4];
        const float4 r5 = win[c0 + i + 5];
        const float4 r6 = win[c0 + i + 6];
        const float4 r7 = win[c0 + i + 7];

#define STEP0(r) { const float dx = qx - (r).x, dy = qy - (r).y;              \
        const float d = __fadd_rn(__fmul_rn(dx, dx), __fmul_rn(dy, dy));      \
        const bool c = (d < bd0) || (d == bd0 && (r).z < bz0);                \
        bd0 = c ? d : bd0; bz0 = c ? (r).z : bz0; }
#define STEP1(r) { const float dx = qx - (r).x, dy = qy - (r).y;              \
        const float d = __fadd_rn(__fmul_rn(dx, dx), __fmul_rn(dy, dy));      \
        const bool c = (d < bd1) || (d == bd1 && (r).z < bz1);                \
        bd1 = c ? d : bd1; bz1 = c ? (r).z : bz1; }
        STEP0(r0) STEP1(r1) STEP0(r2) STEP1(r3)
        STEP0(r4) STEP1(r5) STEP0(r6) STEP1(r7)
#undef STEP0
#undef STEP1
    }
    const bool cm = (bd1 < bd0) || (bd1 == bd0 && bz1 < bz0);
    pbd[s][L] = cm ? bd1 : bd0;
    pbz[s][L] = cm ? bz1 : bz0;
    __syncthreads();

    if (t < QPB) {                       // wave 0: combine, certify, write
        float best = pbd[0][L];
        float bif  = pbz[0][L];
#pragma unroll
        for (int k = 1; k < 4; ++k) {
            const float dv = pbd[k][L];
            const float zv = pbz[k][L];
            const bool c = (dv < best) || (dv == best && zv < bif);
            best = c ? dv : best;
            bif  = c ? zv : bif;
        }

        // exact-conservative certification at the UNION edges:
        //  all p<u0 have x <= right_edge(bucket(x[u0-1])) and
        //  d >= fl(dx^2) >= fl(dxe^2) > best => can't beat or tie
        const int wr = u0 + UNI;
        bool okL = (u0 == 0), okR = (wr >= NPTS);
        if (!okL) {
            const int kl = bucket_of(Rf[u0 - 1].x);
            if (kl < NBUK - 1) {
                const float dxe = qx - (XLO + (float)(kl + 1) * XW);
                okL = (dxe > 0.0f) && (__fmul_rn(dxe, dxe) > best);
            }
        }
        if (!okR) {
            const int kr = bucket_of(Rf[wr].x);
            if (kr > 0) {
                const float dxe = (XLO + (float)kr * XW) - qx;
                okR = (dxe > 0.0f) && (__fmul_rn(dxe, dxe) > best);
            }
        }

        const int qid = (int)q.z;
        const int od  = b * 8192 + qid;
        if (dir == 0) { out[od]         = best; out[65536 + od] = bif; }
        else          { out[32768 + od] = best; out[98304 + od] = bif; }

        if (!(okL && okR)) {
            const int pos = atomicAdd(cnt, 1);
            queue[pos] = q0slot + L;     // db*8192 + qpos
        }
    }
}

// ---- 3) y-pass: one wave per queued query (2048 waves) --------------------
__global__ __launch_bounds__(256) void ypass_kernel(
    const float4* __restrict__ bpts, const float4* __restrict__ ypts,
    const int* __restrict__ ystarts, const float* __restrict__ in1,
    const float* __restrict__ in2, const int* __restrict__ cnt,
    const int* __restrict__ queue, float* __restrict__ out)
{
    const int n    = *cnt;
    const int gw   = (blockIdx.x << 2) + (threadIdx.x >> 6);
    const int lane = threadIdx.x & 63;

    for (int item = gw; item < n; item += 2048) {
        const int qslot = queue[item];
        const int qpos  = qslot & 8191;
        const int db    = qslot >> 13;
        const int dir   = db >> 2;
        const int b     = db & 3;
        const int qsb   = (dir ? 4 : 0) + b;
        const int rsb   = (dir ? 0 : 4) + b;

        const float4 q = bpts[(size_t)qsb * NPTS + qpos];
        const float qx = q.x, qy = q.y;
        const int qid  = (int)q.z;
        const int od   = b * 8192 + qid;

        // carried pass-1 lex-min (over the x-union)
        float best = (dir == 0) ? out[od]         : out[32768 + od];
        float bif  = (dir == 0) ? out[65536 + od] : out[98304 + od];

        // y-rank window centered via ystarts
        const float4* __restrict__ Y  = ypts + (size_t)rsb * NPTS;
        const int* __restrict__ ys    = ystarts + rsb * (NBUK + 1);
        const int kq = bucket_of(qy);
        int wl = ((ys[kq] + ys[kq + 1]) >> 1) - YWIN / 2;
        wl = wl < 0 ? 0 : (wl > NPTS - YWIN ? NPTS - YWIN : wl);

        // scan 512 y-ranked candidates: lane + 64*i, coalesced
        float bd = 1e30f, bz = 0.0f;
#pragma unroll
        for (int i = 0; i < 8; ++i) {
            const float4 r = Y[wl + lane + (i << 6)];
            const float dx = qx - r.x;
            const float dy = qy - r.y;
            const float d = __fadd_rn(__fmul_rn(dx, dx), __fmul_rn(dy, dy));
            const bool c = (d < bd) || (d == bd && r.z < bz);
            bd = c ? d : bd;
            bz = c ? r.z : bz;
        }
        // butterfly lex reduce -> all lanes hold the window min
#pragma unroll
        for (int m = 1; m < 64; m <<= 1) {
            const float od_ = __shfl_xor(bd, m, 64);
            const float oz_ = __shfl_xor(bz, m, 64);
            const bool c = (od_ < bd) || (od_ == bd && oz_ < bz);
            bd = c ? od_ : bd;
            bz = c ? oz_ : bz;
        }
        // combine with carried best
        {
            const bool c = (bd < best) || (bd == best && bz < bif);
            best = c ? bd : best;
            bif  = c ? bz : bif;
        }

        // y-edge certification (sufficient alone: any unscanned point p has
        // y-gap >= dye => d >= fl(dy^2) >= fl(dye^2) > best)
        const int wr = wl + YWIN;
        bool okL = (wl == 0), okR = (wr >= NPTS);
        if (!okL) {
            const int kl = bucket_of(Y[wl - 1].y);
            if (kl < NBUK - 1) {
                const float dye = qy - (XLO + (float)(kl + 1) * XW);
                okL = (dye > 0.0f) && (__fmul_rn(dye, dye) > best);
            }
        }
        if (!okR) {
            const int kr = bucket_of(Y[wr].y);
            if (kr > 0) {
                const float dye = (XLO + (float)kr * XW) - qy;
                okR = (dye > 0.0f) && (__fmul_rn(dye, dye) > best);
            }
        }

        if (!(okL && okR)) {
            // double-fail: exact brute force over idx-ordered original array.
            // per-lane j ascends -> strict < keeps first occurrence in-lane.
            const float2* __restrict__ P =
                (const float2*)((dir ? in1 : in2) + (size_t)b * NPTS * 2);
            float fbd = 1e30f, fbz = 0.0f;
#pragma unroll 4
            for (int j = lane; j < NPTS; j += 64) {
                const float2 rp = P[j];
                const float dx = qx - rp.x;
                const float dy = qy - rp.y;
                const float d = __fadd_rn(__fmul_rn(dx, dx), __fmul_rn(dy, dy));
                const bool c = d < fbd;
                fbd = c ? d : fbd;
                fbz = c ? (float)j : fbz;
            }
#pragma unroll
            for (int m = 1; m < 64; m <<= 1) {
                const float od_ = __shfl_xor(fbd, m, 64);
                const float oz_ = __shfl_xor(fbz, m, 64);
                const bool c = (od_ < fbd) || (od_ == fbd && oz_ < fbz);
                fbd = c ? od_ : fbd;
                fbz = c ? oz_ : fbz;
            }
            best = fbd;
            bif  = fbz;
        }

        if (lane == 0) {
            if (dir == 0) { out[od]         = best; out[65536 + od] = bif; }
            else          { out[32768 + od] = best; out[98304 + od] = bif; }
        }
    }
}

extern "C" void kernel_launch(void* const* d_in, const int* in_sizes, int n_in,
                              void* d_out, int out_size, void* d_ws, size_t ws_size,
                              hipStream_t stream) {
    const float* in1 = (const float*)d_in[0];
    const float* in2 = (const float*)d_in[1];
    float* out = (float*)d_out;
    (void)in_sizes; (void)n_in; (void)out_size; (void)ws_size;

    // ws: bpts 1MiB | ypts 1MiB | ystarts 8*1025*4 | cnt 4 | queue 65536*4
    char* w = (char*)d_ws;
    float4* bpts = (float4*)w;
    float4* ypts = (float4*)(w + (size_t)8 * NPTS * sizeof(float4));
    int* ystarts = (int*)(w + (size_t)16 * NPTS * sizeof(float4));
    int* cnt     = ystarts + 8 * (NBUK + 1);
    int* queue   = cnt + 1;

    bucketize_kernel<<<16, 1024, 0, stream>>>(in1, in2, bpts, ypts, ystarts, cnt);
    window_scan_kernel<<<(2 * 4 * NPTS) / QPB, 256, 0, stream>>>(bpts, out, cnt, queue);
    ypass_kernel<<<512, 256, 0, stream>>>(bpts, ypts, ystarts, in1, in2,
                                          cnt, queue, out);
}